// Round 13
// baseline (165.064 us; speedup 1.0000x reference)
//
#include <hip/hip_runtime.h>
#include <hip/hip_bf16.h>

typedef _Float16 half8 __attribute__((ext_vector_type(8)));
typedef _Float16 half4 __attribute__((ext_vector_type(4)));
typedef float f32x4 __attribute__((ext_vector_type(4)));

namespace {

constexpr int INW  = 87;
constexpr int ROWS = 128;   // rows per block (one round: 256 blocks on 256 CUs)
constexpr int NT   = 512;   // 8 waves; wave tile = 128 rows x 32 cols
constexpr int NSLICES = 76; // 3(WE) + 1(WD) + 64(heads) + 8(fc3)

// ws layout (fp16 halves), n-major [256][Kpad], 16B aligned
constexpr long O_WE  = 0;       // [256][96]: k<77 fold(Wfc1@Wenc), k==77 bias row
constexpr long O_WD  = 24576;   // [256][32]: k<10 fold(Wfc2@Wdec), k==10 bias row
constexpr long O_HDS = 32768;   // 8 x [256][256], fc3 contiguous after
constexpr long O_FC3 = 557056;  // = O_HDS + 8*65536
constexpr long CONV_TOTAL = 589824;

__device__ __forceinline__ int aidx(int row, int col) {
  return row * 256 + ((((col >> 3) ^ (row & 7)) << 3) | (col & 7));
}

// ---------------- prep kernels (unchanged) ----------------
__global__ __launch_bounds__(256)
void prep_fold_enc(const float* __restrict__ Wfc1, const float* __restrict__ bfc1,
                   const float* __restrict__ Wenc, const float* __restrict__ benc,
                   _Float16* __restrict__ ws)
{
  const int t = (int)blockIdx.x * 256 + (int)threadIdx.x;
  const int n = t & 255, k = t >> 8;
  float acc = 0.f;
  if (k < 77) {
    for (int m = 0; m < 256; ++m) acc += Wfc1[(size_t)k * 256 + m] * Wenc[(size_t)m * 256 + n];
  } else if (k == 77) {
    for (int m = 0; m < 256; ++m) acc += bfc1[m] * Wenc[(size_t)m * 256 + n];
    acc += benc[n];
  }
  ws[O_WE + (long)n * 96 + k] = (_Float16)acc;
}

__global__ __launch_bounds__(256)
void prep_fold_dec(const float* __restrict__ Wfc2, const float* __restrict__ bfc2,
                   const float* __restrict__ Wdec, const float* __restrict__ bdec,
                   _Float16* __restrict__ ws)
{
  const int t = (int)blockIdx.x * 256 + (int)threadIdx.x;
  const int n = t & 255, k = t >> 8;
  float acc = 0.f;
  if (k < 10) {
    for (int m = 0; m < 256; ++m) acc += Wfc2[(size_t)k * 256 + m] * Wdec[(size_t)m * 256 + n];
  } else if (k == 10) {
    for (int m = 0; m < 256; ++m) acc += bfc2[m] * Wdec[(size_t)m * 256 + n];
    acc += bdec[n];
  }
  ws[O_WD + (long)n * 32 + k] = (_Float16)acc;
}

__global__ __launch_bounds__(256)
void prep_conv(const float* __restrict__ Whds, const float* __restrict__ Wfc3,
               _Float16* __restrict__ ws)
{
  const long t = (long)blockIdx.x * 256 + threadIdx.x;
  const long e = t * 4;
  if (e >= CONV_TOTAL) return;
  const int h = (int)(e >> 16);
  const float* src = (h < 8) ? (Whds + ((long)h << 16)) : Wfc3;
  const long le = e & 65535;
  const int n = (int)(le >> 8), k0 = (int)(le & 255);
  half4 v;
#pragma unroll
  for (int j = 0; j < 4; ++j)
    v[j] = (_Float16)src[(size_t)(k0 + j) * 256 + n];
  *(half4*)&ws[O_HDS + e] = v;
}

// lgkm-only barrier: LDS visibility; global B prefetches stay in flight
__device__ __forceinline__ void sync_lgkm() {
  asm volatile("s_waitcnt lgkmcnt(0)" ::: "memory");
  __builtin_amdgcn_s_barrier();
}

typedef const __attribute__((address_space(1))) half8* gptr8;

// =========================== main fused kernel ===========================
__global__ __launch_bounds__(NT)
__attribute__((amdgpu_waves_per_eu(2)))
void fused_mfma(const float* __restrict__ x,
                const float* __restrict__ bhds,
                const float* __restrict__ bfc3,
                const float* __restrict__ Wq,  const float* __restrict__ bq,
                const int* __restrict__ agent,
                const _Float16* __restrict__ ws,
                float* __restrict__ out)
{
  __shared__ _Float16 A[ROWS * 256];        // 64 KB
  __shared__ float sp[2][8][ROWS];          // 8 KB

  const int tid  = (int)threadIdx.x;
  const int lane = tid & 63;
  const int wn   = tid >> 6;        // 0..7 : this wave's 32-col stripe
  const int l15  = lane & 15;
  const int l4   = lane >> 4;
  const int cbase = wn * 32;
  const int row0 = (int)blockIdx.x * ROWS;
  const int a = agent[0];

  auto loadBraw = [&](const _Float16* b, int Klen, int k0, half8& qa, half8& qb) {
    const _Float16* p = b + (long)(cbase + l15) * Klen + k0 + (long)l4 * 8;
    qa = *(gptr8)p;
    qb = *(gptr8)(p + (long)16 * Klen);
  };
  // heads+fc3 contiguous region: slice i in [4,76) -> matrix (i-4)>>3
  auto loadBH = [&](int i, half8& qa, half8& qb) {
    const int t = (i < 75 ? i : 75) - 4;
    loadBraw(ws + O_HDS + (long)(t >> 3) * 65536, 256, (t & 7) * 32, qa, qb);
  };
  auto loadBany = [&](int i, half8& qa, half8& qb) {
    if (i < 3)       loadBraw(ws + O_WE, 96, i * 32, qa, qb);
    else if (i == 3) loadBraw(ws + O_WD, 32, 0, qa, qb);
    else             loadBH(i, qa, qb);
  };
  auto ldAF = [&](half8 (&af)[8], int acol) {
#pragma unroll
    for (int mt = 0; mt < 8; ++mt) {
      const int row = mt * 16 + l15;
      const int cch = (acol >> 3) + l4;
      af[mt] = *(const half8*)&A[row * 256 + ((cch ^ (row & 7)) << 3)];
    }
  };
  auto mfma16 = [&](const half8 (&af)[8], const half8& ba, const half8& bb,
                    f32x4 (&acc)[8][2]) {
#pragma unroll
    for (int mt = 0; mt < 8; ++mt) {
      acc[mt][0] = __builtin_amdgcn_mfma_f32_16x16x32_f16(af[mt], ba, acc[mt][0], 0, 0, 0);
      acc[mt][1] = __builtin_amdgcn_mfma_f32_16x16x32_f16(af[mt], bb, acc[mt][1], 0, 0, 0);
    }
  };
  auto zeroAcc = [&](f32x4 (&acc)[8][2]) {
#pragma unroll
    for (int mt = 0; mt < 8; ++mt)
#pragma unroll
      for (int nt = 0; nt < 2; ++nt) acc[mt][nt] = { 0.f, 0.f, 0.f, 0.f };
  };
  auto writeA = [&](const f32x4 (&acc)[8][2], bool relu) {
#pragma unroll
    for (int mt = 0; mt < 8; ++mt)
#pragma unroll
      for (int nt = 0; nt < 2; ++nt)
#pragma unroll
        for (int r = 0; r < 4; ++r) {
          float v = acc[mt][nt][r];
          if (relu) v = fmaxf(v, 0.f);
          A[aidx(mt * 16 + l4 * 4 + r, cbase + nt * 16 + l15)] = (_Float16)v;
        }
  };

  // ---- depth-2 B pipeline prologue ----
  half8 q0a, q0b, q1a, q1b;
  loadBany(0, q0a, q0b); loadBany(1, q1a, q1b);

  // ---- build A0 (cols 0..127): enc-in 0..76, 77=1, dec-others 96..105, 106=1 ----
  for (int i = tid; i < ROWS * 128; i += NT) {
    const int r = i >> 7, c = i & 127;
    float v = 0.f;
    const size_t xb = (size_t)(row0 + r) * INW;
    if (c < 72)            v = x[xb + c];
    else if (c < 77)       v = x[xb + 72 + 5 * a + (c - 72)];
    else if (c == 77)      v = 1.f;
    else if (c >= 96 && c < 106) {
      const int o = c - 96;
      v = x[xb + 72 + (o < 5 * a ? o : o + 5)];
    }
    else if (c == 106)     v = 1.f;
    A[aidx(r, c)] = (_Float16)v;
  }
  sync_lgkm();

  // ---- prologue GEMMs: enc pre-relu -> ctx ; dec pre-relu -> acc ----
  f32x4 ctx[8][2], acc[8][2];
  zeroAcc(ctx); zeroAcc(acc);
  {
    half8 af[8];
    ldAF(af, 0);  mfma16(af, q0a, q0b, ctx); loadBany(2, q0a, q0b);
    ldAF(af, 32); mfma16(af, q1a, q1b, ctx); loadBany(3, q1a, q1b);
    ldAF(af, 64); mfma16(af, q0a, q0b, ctx); loadBany(4, q0a, q0b);
    ldAF(af, 96); mfma16(af, q1a, q1b, acc); loadBany(5, q1a, q1b);
  }

  half4 dpk[8][2];            // dec_H = relu, packed fp16
#pragma unroll
  for (int mt = 0; mt < 8; ++mt)
#pragma unroll
    for (int nt = 0; nt < 2; ++nt)
      dpk[mt][nt] = half4{ (_Float16)fmaxf(acc[mt][nt][0], 0.f),
                           (_Float16)fmaxf(acc[mt][nt][1], 0.f),
                           (_Float16)fmaxf(acc[mt][nt][2], 0.f),
                           (_Float16)fmaxf(acc[mt][nt][3], 0.f) };

  sync_lgkm();                // all waves' A0 reads done
  writeA(ctx, true);          // A := enc_h = relu(enc pre-relu)
  zeroAcc(ctx);
  sync_lgkm();                // enc_h visible

  // ---- heads + online softmax (reference = head-0 score) ----
  // softmax state: lane owns rows lane (lo) and lane+64 (hi)
  float s0lo = 0.f, s0hi = 0.f, lslo = 1.f, lshi = 1.f;

  for (int h = 0; h < 8; ++h) {
    const int base = 4 + 8 * h;
    const float bh0 = bhds[h * 256 + cbase + l15];
    const float bh1 = bhds[h * 256 + cbase + 16 + l15];

    zeroAcc(acc);
    {
      half8 af[8];
      ldAF(af, 0);   mfma16(af, q0a, q0b, acc); loadBH(base + 2, q0a, q0b);
      ldAF(af, 32);  mfma16(af, q1a, q1b, acc); loadBH(base + 3, q1a, q1b);
      ldAF(af, 64);  mfma16(af, q0a, q0b, acc); loadBH(base + 4, q0a, q0b);
      ldAF(af, 96);  mfma16(af, q1a, q1b, acc); loadBH(base + 5, q1a, q1b);
      ldAF(af, 128); mfma16(af, q0a, q0b, acc); loadBH(base + 6, q0a, q0b);
      ldAF(af, 160); mfma16(af, q1a, q1b, acc); loadBH(base + 7, q1a, q1b);
      ldAF(af, 192); mfma16(af, q0a, q0b, acc); loadBH(base + 8, q0a, q0b);
      ldAF(af, 224); mfma16(af, q1a, q1b, acc); loadBH(base + 9, q1a, q1b);
    }

    // bias + relu, then score partials over this wave's 32 cols
    float p[8][4];
#pragma unroll
    for (int mt = 0; mt < 8; ++mt)
#pragma unroll
      for (int r = 0; r < 4; ++r) {
        acc[mt][0][r] = fmaxf(acc[mt][0][r] + bh0, 0.f);
        acc[mt][1][r] = fmaxf(acc[mt][1][r] + bh1, 0.f);
        p[mt][r] = fmaf(acc[mt][0][r], (float)dpk[mt][0][r],
                        acc[mt][1][r] * (float)dpk[mt][1][r]);
      }
#pragma unroll
    for (int off = 1; off < 16; off <<= 1)
#pragma unroll
      for (int mt = 0; mt < 8; ++mt)
#pragma unroll
        for (int r = 0; r < 4; ++r)
          p[mt][r] += __shfl_xor(p[mt][r], off, 64);
    if (l15 == 0) {
#pragma unroll
      for (int mt = 0; mt < 8; ++mt)
#pragma unroll
        for (int r = 0; r < 4; ++r)
          sp[h & 1][wn][mt * 16 + l4 * 4 + r] = p[mt][r];
    }
    sync_lgkm();              // sp visible; B prefetches stay in flight

    float sh0 = 0.f, sh1 = 0.f;
#pragma unroll
    for (int w = 0; w < 8; ++w) {
      sh0 += sp[h & 1][w][lane];
      sh1 += sp[h & 1][w][64 + lane];
    }
    float w0, w1;
    if (h == 0) { s0lo = sh0; s0hi = sh1; lslo = 1.f; lshi = 1.f; w0 = 1.f; w1 = 1.f; }
    else {
      w0 = __expf(fminf(sh0 - s0lo, 70.f)); lslo += w0;
      w1 = __expf(fminf(sh1 - s0hi, 70.f)); lshi += w1;
    }

    // redistribute weight to the (mt,r) holders of each row
#pragma unroll
    for (int mt = 0; mt < 8; ++mt)
#pragma unroll
      for (int r = 0; r < 4; ++r) {
        const int src = (mt * 16 + l4 * 4 + r) & 63;
        const float wgt = __shfl(mt < 4 ? w0 : w1, src, 64);
        ctx[mt][0][r] = fmaf(wgt, acc[mt][0][r], ctx[mt][0][r]);
        ctx[mt][1][r] = fmaf(wgt, acc[mt][1][r], ctx[mt][1][r]);
      }
    // sp[h&1] reused at h+2; fenced by head h+1's barrier
  }

  // normalize context
  {
    const float i0 = 1.f / lslo, i1 = 1.f / lshi;
#pragma unroll
    for (int mt = 0; mt < 8; ++mt)
#pragma unroll
      for (int r = 0; r < 4; ++r) {
        const int src = (mt * 16 + l4 * 4 + r) & 63;
        const float inv = __shfl(mt < 4 ? i0 : i1, src, 64);
        ctx[mt][0][r] *= inv;
        ctx[mt][1][r] *= inv;
      }
  }
  writeA(ctx, false);         // A := context (head-7 reads fenced by its barrier)
  sync_lgkm();

  // ---- fc3 (+bias+relu) then @ Wq ----
  const float bf30 = bfc3[cbase + l15], bf31 = bfc3[cbase + 16 + l15];
  const float wq0  = Wq[cbase + l15],   wq1  = Wq[cbase + 16 + l15];
  zeroAcc(acc);
  {
    half8 af[8];
    // entering: q0 = slice 68 (fc3 k0), q1 = slice 69 (loaded during head 7)
    ldAF(af, 0);   mfma16(af, q0a, q0b, acc); loadBH(70, q0a, q0b);
    ldAF(af, 32);  mfma16(af, q1a, q1b, acc); loadBH(71, q1a, q1b);
    ldAF(af, 64);  mfma16(af, q0a, q0b, acc); loadBH(72, q0a, q0b);
    ldAF(af, 96);  mfma16(af, q1a, q1b, acc); loadBH(73, q1a, q1b);
    ldAF(af, 128); mfma16(af, q0a, q0b, acc); loadBH(74, q0a, q0b);
    ldAF(af, 160); mfma16(af, q1a, q1b, acc); loadBH(75, q1a, q1b);
    ldAF(af, 192); mfma16(af, q0a, q0b, acc);
    ldAF(af, 224); mfma16(af, q1a, q1b, acc);
  }

  float p[8][4];
#pragma unroll
  for (int mt = 0; mt < 8; ++mt)
#pragma unroll
    for (int r = 0; r < 4; ++r)
      p[mt][r] = fmaf(fmaxf(acc[mt][0][r] + bf30, 0.f), wq0,
                      fmaxf(acc[mt][1][r] + bf31, 0.f) * wq1);
#pragma unroll
  for (int off = 1; off < 16; off <<= 1)
#pragma unroll
    for (int mt = 0; mt < 8; ++mt)
#pragma unroll
      for (int r = 0; r < 4; ++r)
        p[mt][r] += __shfl_xor(p[mt][r], off, 64);
  if (l15 == 0) {
#pragma unroll
    for (int mt = 0; mt < 8; ++mt)
#pragma unroll
      for (int r = 0; r < 4; ++r)
        sp[0][wn][mt * 16 + l4 * 4 + r] = p[mt][r];
  }
  sync_lgkm();
  if (tid < ROWS) {
    float v = bq[0];
#pragma unroll
    for (int w = 0; w < 8; ++w) v += sp[0][w][tid];
    out[row0 + tid] = v;
  }
}

}  // namespace

extern "C" void kernel_launch(void* const* d_in, const int* in_sizes, int n_in,
                              void* d_out, int out_size, void* d_ws, size_t ws_size,
                              hipStream_t stream) {
  const float* x    = (const float*)d_in[0];
  const float* Wfc1 = (const float*)d_in[1];
  const float* bfc1 = (const float*)d_in[2];
  const float* Wfc2 = (const float*)d_in[3];
  const float* bfc2 = (const float*)d_in[4];
  const float* Wenc = (const float*)d_in[5];
  const float* benc = (const float*)d_in[6];
  const float* Whds = (const float*)d_in[7];
  const float* bhds = (const float*)d_in[8];
  const float* Wdec = (const float*)d_in[9];
  const float* bdec = (const float*)d_in[10];
  const float* Wfc3 = (const float*)d_in[11];
  const float* bfc3 = (const float*)d_in[12];
  const float* Wq   = (const float*)d_in[13];
  const float* bq   = (const float*)d_in[14];
  const int*  agent = (const int*)d_in[15];
  float* out = (float*)d_out;
  _Float16* ws = (_Float16*)d_ws;

  const int Bn = in_sizes[0] / INW;         // 32768
  const int grid = Bn / ROWS;               // 256 blocks = 1 per CU, one round

  prep_fold_enc<<<96, 256, 0, stream>>>(Wfc1, bfc1, Wenc, benc, ws);
  prep_fold_dec<<<32, 256, 0, stream>>>(Wfc2, bfc2, Wdec, bdec, ws);
  prep_conv<<<(int)((CONV_TOTAL / 4 + 255) / 256), 256, 0, stream>>>(Whds, Wfc3, ws);
  fused_mfma<<<grid, NT, 0, stream>>>(x, bhds, bfc3, Wq, bq, agent, ws, out);
}